// Round 5
// baseline (21.453 us; speedup 1.0000x reference)
//
#include <hip/hip_runtime.h>

// CropPool2D: out[b,c] = mean over bbox[b] region of img[b,c,:,:]
// img: (B, C, H, W) fp32; bboxes: (B,4) int32; out: (B,C) fp32
// One 64-lane wave per (b,c) pair. CONTIGUOUS-SWEEP variant: read the whole
// row range [y1*W, y2*W) of the plane (one contiguous ~3.2KB extent) with
// aligned float4 loads; mask out-of-box columns in registers. Trades +22%
// fetched bytes for streaming-efficiency bursts. No XCD swizzle (R4: -6%).

#define WAVES_PER_BLOCK 4

__global__ __launch_bounds__(256) void croppool2d_kernel(
    const float* __restrict__ img,
    const int* __restrict__ bboxes,
    float* __restrict__ out,
    int npairs) {

    constexpr int H = 56, W = 56;
    const int wid  = threadIdx.x >> 6;
    const int lane = threadIdx.x & 63;
    const int pair = blockIdx.x * WAVES_PER_BLOCK + wid;   // = b*C + c

    __shared__ float wsum[WAVES_PER_BLOCK];

    if (pair < npairs) {
        const int b = pair >> 9;                           // / C (C=512)
        const int4 bb = *(const int4*)(bboxes + b * 4);
        const int x1 = bb.x, y1 = bb.y, x2 = bb.z, y2 = bb.w;
        const int wbox = x2 - x1;                          // 1..28
        const int area = wbox * (y2 - y1);                 // 1..784
        const int count = (y2 - y1) * W;                   // floats to sweep, <=1568 (y2<=55)

        // Contiguous extent start: plane base + y1*W (16B-aligned: y1*224%16==0)
        const float4* base = (const float4*)(img + (size_t)pair * (H * W) + y1 * W);

        // x0 = (lane*4) mod 56, then advances by +32 mod 56 per round.
        // 56%4==0 -> a float4 never straddles a row; x0 stays a multiple of 4.
        const int t0 = lane * 4;
        int x0 = t0 - 56 * (int)((float)t0 * (1.0f / 56.0f) + 0.001f);

        float sum = 0.0f;

        // Batch A: rounds 0..3 (covers count <= 1024), independent clamped loads.
        float4 v[4]; int xr[4]; int tv[4];
        #pragma unroll
        for (int i = 0; i < 4; ++i) {
            const int idx = lane + i * 64;                 // float4 index
            const int tf  = idx * 4;                       // flat float index
            tv[i] = tf;
            v[i]  = base[(tf < count) ? idx : 0];          // clamped, always executes
            xr[i] = x0;
            x0 += 32; if (x0 >= 56) x0 -= 56;
        }
        #pragma unroll
        for (int i = 0; i < 4; ++i) {
            const int rowok = (tv[i] < count);             // whole float4 same row
            #pragma unroll
            for (int j = 0; j < 4; ++j) {
                const bool use = rowok && ((unsigned)(xr[i] + j - x1) < (unsigned)wbox);
                sum += use ? (&v[i].x)[j] : 0.0f;
            }
        }

        // Batch B: rounds 4..6 (only when count > 1024; max count 1568).
        if (count > 1024) {                                // block-uniform branch
            float4 v2[3]; int xr2[3]; int tv2[3];
            #pragma unroll
            for (int i = 0; i < 3; ++i) {
                const int idx = lane + (i + 4) * 64;
                const int tf  = idx * 4;
                tv2[i] = tf;
                v2[i]  = base[(tf < count) ? idx : 0];
                xr2[i] = x0;
                x0 += 32; if (x0 >= 56) x0 -= 56;
            }
            #pragma unroll
            for (int i = 0; i < 3; ++i) {
                const int rowok = (tv2[i] < count);
                #pragma unroll
                for (int j = 0; j < 4; ++j) {
                    const bool use = rowok && ((unsigned)(xr2[i] + j - x1) < (unsigned)wbox);
                    sum += use ? (&v2[i].x)[j] : 0.0f;
                }
            }
        }

        // 64-lane butterfly reduce
        #pragma unroll
        for (int off = 32; off > 0; off >>= 1)
            sum += __shfl_xor(sum, off, 64);

        if (lane == 0)
            wsum[wid] = sum / (float)area;
    }

    __syncthreads();

    // Coalesced store of the block's 4 results
    const int opair = blockIdx.x * WAVES_PER_BLOCK + threadIdx.x;
    if (threadIdx.x < WAVES_PER_BLOCK && opair < npairs)
        out[opair] = wsum[threadIdx.x];
}

extern "C" void kernel_launch(void* const* d_in, const int* in_sizes, int n_in,
                              void* d_out, int out_size, void* d_ws, size_t ws_size,
                              hipStream_t stream) {
    const float* img    = (const float*)d_in[0];
    const int*   bboxes = (const int*)d_in[1];
    float*       out    = (float*)d_out;

    const int npairs = out_size;                           // B*C = 32768
    const int blocks = (npairs + WAVES_PER_BLOCK - 1) / WAVES_PER_BLOCK;
    croppool2d_kernel<<<blocks, 256, 0, stream>>>(img, bboxes, out, npairs);
}

// Round 6
// 18.774 us; speedup vs baseline: 1.1427x; 1.1427x over previous
//
#include <hip/hip_runtime.h>

// CropPool2D: out[b,c] = mean over bbox[b] region of img[b,c,:,:]
// img: (B, C, H, W) fp32; bboxes: (B,4) int32; out: (B,C) fp32
// One 64-lane wave per (b,c) pair. Revert to R3 structure (best, 18.68us):
// tiered rounds of 4 clamped independent loads (block-uniform trip count),
// rcp-based exact floor-div, division-free flattened walk, 64-lane shuffle
// reduce, LDS-combined coalesced store. Added: nontemporal image loads
// (zero reuse -> skip cache allocation). No XCD swizzle (R4: -6%), no
// contiguous sweep (R5: +15% bytes beats burst gain).

#define WAVES_PER_BLOCK 4

__global__ __launch_bounds__(256) void croppool2d_kernel(
    const float* __restrict__ img,
    const int* __restrict__ bboxes,
    float* __restrict__ out,
    int npairs) {

    constexpr int H = 56, W = 56;
    const int wid  = threadIdx.x >> 6;
    const int lane = threadIdx.x & 63;
    const int pair = blockIdx.x * WAVES_PER_BLOCK + wid;   // = b*C + c

    __shared__ float wsum[WAVES_PER_BLOCK];

    if (pair < npairs) {
        const int b = pair >> 9;                           // / C (C=512)
        const int4 bb = *(const int4*)(bboxes + b * 4);
        const int x1 = bb.x, y1 = bb.y, x2 = bb.z, y2 = bb.w;
        const int wbox = x2 - x1;                          // 1..28
        const int area = wbox * (y2 - y1);                 // 1..784

        const float* base = img + (size_t)pair * (H * W) + y1 * W + x1;

        // Exact small-operand floor-div via v_rcp_f32 (args <=64 / <=28;
        // rel-err ~2^-22 << 1/28 boundary margin; +0.001 handles exact ints).
        const float r = __builtin_amdgcn_rcpf((float)wbox);
        int dy = (int)((float)lane * r + 0.001f);
        int dx = lane - dy * wbox;
        int addr = dy * W + dx;
        const int qd = (int)(64.0f * r + 0.001f);          // 64 / wbox
        const int qr = 64 - qd * wbox;                     // 64 % wbox
        const int stepA = qd * W + qr;
        const int rowFix = W - wbox;

        float sum = 0.0f;
        int t = lane;

        // Rounds of 4 independent clamped loads; trip count is wave-uniform
        // (area depends only on b; all 4 waves in a block share b).
        for (int done = 0; done < area; done += 256) {
            float v[4]; int ok[4];
            #pragma unroll
            for (int i = 0; i < 4; ++i) {
                ok[i] = (t < area);
                v[i]  = __builtin_nontemporal_load(base + (ok[i] ? addr : 0));
                t += 64;
                dx += qr; addr += stepA;
                if (dx >= wbox) { dx -= wbox; addr += rowFix; }
            }
            #pragma unroll
            for (int i = 0; i < 4; ++i)
                sum += ok[i] ? v[i] : 0.0f;
        }

        // 64-lane butterfly reduce
        #pragma unroll
        for (int off = 32; off > 0; off >>= 1)
            sum += __shfl_xor(sum, off, 64);

        if (lane == 0)
            wsum[wid] = sum / (float)area;
    }

    __syncthreads();

    // Coalesced store of the block's 4 results
    const int opair = blockIdx.x * WAVES_PER_BLOCK + threadIdx.x;
    if (threadIdx.x < WAVES_PER_BLOCK && opair < npairs)
        out[opair] = wsum[threadIdx.x];
}

extern "C" void kernel_launch(void* const* d_in, const int* in_sizes, int n_in,
                              void* d_out, int out_size, void* d_ws, size_t ws_size,
                              hipStream_t stream) {
    const float* img    = (const float*)d_in[0];
    const int*   bboxes = (const int*)d_in[1];
    float*       out    = (float*)d_out;

    const int npairs = out_size;                           // B*C = 32768
    const int blocks = (npairs + WAVES_PER_BLOCK - 1) / WAVES_PER_BLOCK;
    croppool2d_kernel<<<blocks, 256, 0, stream>>>(img, bboxes, out, npairs);
}